// Round 9
// baseline (501.116 us; speedup 1.0000x reference)
//
#include <hip/hip_runtime.h>
#include <hip/hip_bf16.h>
#include <math.h>

typedef __hip_bfloat16 bf16;
typedef __attribute__((ext_vector_type(8))) short s8v;   // 8 bf16 bit-carrier (4 VGPR)
typedef __attribute__((ext_vector_type(4))) float f4v;   // MFMA 16x16 accumulator / float4
typedef __attribute__((ext_vector_type(4))) unsigned short u4v; // 8B bf16 carrier

#define Bn  32
#define Cn  160
#define HWn 3136
#define Pn  100352

__device__ __forceinline__ float b2f(bf16 v){ return __bfloat162float(v); }
__device__ __forceinline__ bf16  f2b(float v){ return __float2bfloat16(v); }
__device__ __forceinline__ float bits2f(unsigned short u){
    union { float f; unsigned int i; } x; x.i = ((unsigned int)u) << 16; return x.f;
}
__device__ __forceinline__ unsigned short f2bits(float v){
    union { unsigned short us; bf16 b; } cv; cv.b = f2b(v); return cv.us;
}
// Fast gelu: erf via Abramowitz-Stegun 7.1.26 (|eps| <= 1.5e-7 absolute on erf).
__device__ __forceinline__ float gelu_f(float x){
    float ax = fabsf(x) * 0.7071067811865476f;
    float t  = 1.0f / (1.0f + 0.3275911f*ax);
    float p  = ((((1.061405429f*t - 1.453152027f)*t + 1.421413741f)*t
                 - 0.284496736f)*t + 0.254829592f)*t;
    float e  = __expf(-ax*ax);
    float erfv = 1.0f - p*e;            // erf(|x|/sqrt2)
    float s = (x >= 0.f) ? erfv : -erfv;
    return 0.5f*x*(1.0f + s);
}

#define MFMA(a,b,c) __builtin_amdgcn_mfma_f32_16x16x32_bf16((a),(b),(c),0,0,0)

// ---------------- K0: weight prep (fp32 -> bf16, concat/pad, LN folding) ----------------
__global__ __launch_bounds__(256) void k0_prep(
    const float* __restrict__ wt, const float* __restrict__ wb_, const float* __restrict__ wr,
    const float* __restrict__ wl, const float* __restrict__ wc,
    const float* __restrict__ bt, const float* __restrict__ bb_, const float* __restrict__ br,
    const float* __restrict__ bl, const float* __restrict__ bc,
    const float* __restrict__ wf1, const float* __restrict__ bf1,
    const float* __restrict__ g2, const float* __restrict__ b2, const float* __restrict__ m2, const float* __restrict__ v2,
    const float* __restrict__ wf2, const float* __restrict__ wfc1, const float* __restrict__ wfc2,
    const float* __restrict__ wph, const float* __restrict__ wpw,
    const float* __restrict__ lng, const float* __restrict__ lnb, const float* __restrict__ bfc1,
    bf16* wcat, bf16* wf1b, bf16* wf2b, bf16* wfc1g, bf16* wfc2b, bf16* wphb, bf16* wpwb,
    float* bcat, float* epsv, float* eptv, float* wgs, float* wcb)
{
    int idx = blockIdx.x*256 + threadIdx.x;
    if (idx < 25600){ int o = idx/160, k = idx - o*160; int gi = o>>5, oo = o&31;
        const float* wp = gi==0?wt: gi==1?wb_: gi==2?wr: gi==3?wl: wc;
        wcat[idx] = f2b(wp[oo*160+k]); return; }
    idx -= 25600;
    if (idx < 25600){ wf1b[idx] = f2b(wf1[idx]); return; }
    idx -= 25600;
    if (idx < 76800){ wf2b[idx] = f2b(wf2[idx]); return; }
    idx -= 76800;
    if (idx < 76800){ int f = idx/160, c = idx - f*160;
        wfc1g[idx] = f2b(wfc1[f*160+c] * lng[c]); return; }
    idx -= 76800;
    if (idx < 76800){ wfc2b[idx] = f2b(wfc2[idx]); return; }
    idx -= 76800;
    if (idx < 4096){ int v = idx>>6, w = idx&63;
        wphb[idx] = (v<56 && w<56) ? f2b(wph[v*56+w]) : f2b(0.f); return; }
    idx -= 4096;
    if (idx < 4096){ int v = idx>>6, w = idx&63;
        wpwb[idx] = (v<56 && w<56) ? f2b(wpw[v*56+w]) : f2b(0.f); return; }
    idx -= 4096;
    if (idx < 160){ int o = idx; int gi = o>>5, oo = o&31;
        const float* bp = gi==0?bt: gi==1?bb_: gi==2?br: gi==3?bl: bc;
        bcat[o] = bp[oo]; return; }
    idx -= 160;
    if (idx < 160){ int o = idx; float s = g2[o]*rsqrtf(v2[o]+1e-5f);
        epsv[o] = s; eptv[o] = (bf1[o]-m2[o])*s + b2[o]; return; }
    idx -= 160;
    if (idx < 480){ int o = idx; float sg = 0.f, sb = 0.f;
        const float* wr_ = wfc1 + (size_t)o*160;
        for (int c = 0; c < 160; ++c){ float w = wr_[c]; sg += w*lng[c]; sb += w*lnb[c]; }
        wgs[o] = sg; wcb[o] = sb + bfc1[o]; return; }
}

// ---------------- K12: fused gelu(bn1(x)) -> LDS A-tile -> conv5 GEMM ----------------
__global__ __launch_bounds__(256) void k12_bn_conv5(const float* __restrict__ x,
    const float* __restrict__ g, const float* __restrict__ b,
    const float* __restrict__ m_, const float* __restrict__ v,
    const bf16* __restrict__ wcat, const float* __restrict__ bcat, bf16* __restrict__ y5T)
{
    __shared__ __align__(16) unsigned short Bs[2][16*168];
    __shared__ __align__(16) char AsB[64*320];
    __shared__ float sc[160], sh[160];
    int tid = threadIdx.x, wave = tid>>6, lane = tid&63, m = lane&15, q = lane>>4;
    int blk = blockIdx.x; int bb = blk/49; int hw0 = (blk - bb*49)*64;
    if (tid < 160){
        float s = g[tid] * rsqrtf(v[tid] + 1e-5f);
        sc[tid] = s; sh[tid] = b[tid] - m_[tid]*s;
    }
    { const s8v* sp = (const s8v*)((const unsigned short*)wcat);
      for (int c = tid; c < 320; c += 256){ int row = c/20, col = (c - row*20)*8;
          *(s8v*)&Bs[0][row*168 + col] = sp[c]; } }
    __syncthreads();   // sc/sh + Bs[0] ready
    const float* xb = x + (size_t)bb*Cn*HWn + hw0;
    for (int idx = tid; idx < 160*64; idx += 256){
        int c = idx >> 6, p = idx & 63;
        float val = xb[(size_t)c*HWn + p];
        unsigned short us = f2bits(gelu_f(val*sc[c] + sh[c]));
        int off = (p*320 + c*2) ^ ((p&7)<<4);
        *(unsigned short*)(AsB + off) = us;
    }
    __syncthreads();   // As ready
    size_t pos0 = (size_t)bb*HWn + hw0;
    s8v a[5];
    {
        int row = wave*16 + m; int xr = (row&7)<<4;
        #pragma unroll
        for (int kb = 0; kb < 5; ++kb){
            int off = (row*320 + (q*8 + kb*32)*2) ^ xr;
            a[kb] = *(const s8v*)(AsB + off);
        }
    }
    for (int s = 0; s < 10; ++s){
        if (s+1 < 10){
            const s8v* sp = (const s8v*)((const unsigned short*)wcat + (size_t)(s+1)*2560);
            for (int c = tid; c < 320; c += 256){ int row = c/20, col = (c - row*20)*8;
                *(s8v*)&Bs[(s+1)&1][row*168 + col] = sp[c]; }
        }
        f4v acc = {0.f,0.f,0.f,0.f};
        const unsigned short* Bp = &Bs[s&1][m*168 + q*8];
        #pragma unroll
        for (int kb = 0; kb < 5; ++kb) acc = MFMA(a[kb], *(const s8v*)(Bp + kb*32), acc);
        float bias = bcat[s*16 + m];
        bf16* yo = y5T + (pos0 + wave*16 + q*4)*160 + s*16 + m;
        #pragma unroll
        for (int r = 0; r < 4; ++r) yo[r*160] = f2b(acc[r] + bias);
        __syncthreads();
    }
}

// ---------------- K3: shifted-A GEMM + bn2 + gelu -> gT ----------------
__global__ __launch_bounds__(256) void k3_wf1(const bf16* __restrict__ y5T,
    const bf16* __restrict__ wf1b, const float* __restrict__ epsv, const float* __restrict__ eptv,
    bf16* __restrict__ gT)
{
    __shared__ __align__(16) unsigned short Bs[2][16*168];
    int tid = threadIdx.x, wave = tid>>6, lane = tid&63, m = lane&15, q = lane>>4;
    int blk = blockIdx.x; int bb = blk/49; int hw0 = (blk - bb*49)*64;
    size_t pos0 = (size_t)bb*HWn + hw0;
    int phw = hw0 + wave*16 + m; int h = phw/56, w = phw - h*56;
    s8v a[5];
    #pragma unroll
    for (int kb = 0; kb < 5; ++kb){
        int h2 = h, w2 = w; bool ok = true;
        if      (kb == 0){ h2 = h+1; ok = (h2 < 56); }
        else if (kb == 1){ h2 = h-1; ok = (h2 >= 0); }
        else if (kb == 2){ w2 = w-1; ok = (w2 >= 0); }
        else if (kb == 3){ w2 = w+1; ok = (w2 < 56); }
        if (ok){
            const unsigned short* Ap = (const unsigned short*)y5T +
                ((size_t)bb*HWn + h2*56 + w2)*160 + kb*32 + q*8;
            a[kb] = *(const s8v*)Ap;
        } else {
            a[kb] = (s8v){0,0,0,0,0,0,0,0};
        }
    }
    { const s8v* sp = (const s8v*)((const unsigned short*)wf1b);
      for (int c = tid; c < 320; c += 256){ int row = c/20, col = (c - row*20)*8;
          *(s8v*)&Bs[0][row*168 + col] = sp[c]; } }
    __syncthreads();
    for (int s = 0; s < 10; ++s){
        if (s+1 < 10){
            const s8v* sp = (const s8v*)((const unsigned short*)wf1b + (size_t)(s+1)*2560);
            for (int c = tid; c < 320; c += 256){ int row = c/20, col = (c - row*20)*8;
                *(s8v*)&Bs[(s+1)&1][row*168 + col] = sp[c]; }
        }
        f4v acc = {0.f,0.f,0.f,0.f};
        const unsigned short* Bp = &Bs[s&1][m*168 + q*8];
        #pragma unroll
        for (int kb = 0; kb < 5; ++kb) acc = MFMA(a[kb], *(const s8v*)(Bp + kb*32), acc);
        int o = s*16 + m;
        float es = epsv[o], et = eptv[o];
        bf16* go = gT + (pos0 + wave*16 + q*4)*160 + o;
        #pragma unroll
        for (int r = 0; r < 4; ++r) go[r*160] = f2b(gelu_f(acc[r]*es + et));
        __syncthreads();
    }
}

// ---------------- K4: proj_h MFMA ----------------
__global__ __launch_bounds__(256) void k4_projh(const bf16* __restrict__ gT,
    const bf16* __restrict__ wphb, const float* __restrict__ bph, bf16* __restrict__ xhT)
{
    __shared__ __align__(16) unsigned short gS[160*72];
    int tid = threadIdx.x, wave = tid>>6, lane = tid&63, m = lane&15, q = lane>>4;
    int blk = blockIdx.x; int b = blk/56, h = blk - b*56;
    const unsigned short* ga = (const unsigned short*)gT + ((size_t)b*HWn + h*56)*160;
    for (int idx = tid; idx < 56*160; idx += 256){
        int w = idx/160, c = idx - w*160;
        gS[c*72 + w] = ga[idx];
    }
    for (int idx = tid; idx < 160*8; idx += 256){
        int c = idx>>3, w = 56 + (idx&7);
        gS[c*72 + w] = 0;
    }
    __syncthreads();
    int v0 = wave*16;
    s8v a[2];
    #pragma unroll
    for (int kb = 0; kb < 2; ++kb)
        a[kb] = *(const s8v*)((const unsigned short*)wphb + (v0+m)*64 + kb*32 + q*8);
    int v = v0 + q*4;
    for (int s = 0; s < 10; ++s){
        f4v acc = {0.f,0.f,0.f,0.f};
        const unsigned short* Bp = &gS[(s*16+m)*72 + q*8];
        #pragma unroll
        for (int kb = 0; kb < 2; ++kb) acc = MFMA(a[kb], *(const s8v*)(Bp + kb*32), acc);
        #pragma unroll
        for (int r = 0; r < 4; ++r){
            int vv = v + r;
            if (vv < 56)
                xhT[((size_t)b*HWn + h*56 + vv)*160 + s*16 + m] = f2b(acc[r] + bph[vv]);
        }
    }
}

// ---------------- K5: proj_w MFMA ----------------
__global__ __launch_bounds__(256) void k5_projw(const bf16* __restrict__ gT,
    const bf16* __restrict__ wpwb, const float* __restrict__ bpw, bf16* __restrict__ xwT)
{
    __shared__ __align__(16) unsigned short gS[160*72];
    int tid = threadIdx.x, wave = tid>>6, lane = tid&63, m = lane&15, q = lane>>4;
    int blk = blockIdx.x; int b = blk/56, w = blk - b*56;
    const unsigned short* gbase = (const unsigned short*)gT + ((size_t)b*HWn + w)*160;
    for (int idx = tid; idx < 56*160; idx += 256){
        int hh = idx/160, c = idx - hh*160;
        gS[c*72 + hh] = gbase[(size_t)hh*56*160 + c];
    }
    for (int idx = tid; idx < 160*8; idx += 256){
        int c = idx>>3, hh = 56 + (idx&7);
        gS[c*72 + hh] = 0;
    }
    __syncthreads();
    int v0 = wave*16;
    s8v a[2];
    #pragma unroll
    for (int kb = 0; kb < 2; ++kb)
        a[kb] = *(const s8v*)((const unsigned short*)wpwb + (v0+m)*64 + kb*32 + q*8);
    int v = v0 + q*4;
    for (int s = 0; s < 10; ++s){
        f4v acc = {0.f,0.f,0.f,0.f};
        const unsigned short* Bp = &gS[(s*16+m)*72 + q*8];
        #pragma unroll
        for (int kb = 0; kb < 2; ++kb) acc = MFMA(a[kb], *(const s8v*)(Bp + kb*32), acc);
        #pragma unroll
        for (int r = 0; r < 4; ++r){
            int vv = v + r;
            if (vv < 56)
                xwT[((size_t)b*HWn + vv*56 + w)*160 + s*16 + m] = f2b(acc[r] + bpw[vv]);
        }
    }
}

// ---------------- K678: fused globalMix-project + channelMix ----------------
// Phase 0 (was k6): gm = wf2 @ concat(gT,xhT,xwT) for this 32-row tile, computed
// per-wave with B direct from L2, bf16 results -> Gs LDS (bit-identical to the
// old k6-write-then-reload). Saves the 64 MB gm HBM round-trip and a dispatch;
// phase 0's MFMA runs in k78's formerly-idle issue slots (60% stall measured).
// Then phases A-D as before: LN in-activation, fc1, fc2 + residual.
__global__ __launch_bounds__(256,3) void k678_mlp(const float* __restrict__ x,
    const bf16* __restrict__ gT, const bf16* __restrict__ xhT, const bf16* __restrict__ xwT,
    const bf16* __restrict__ wf2b,
    const bf16* __restrict__ wfc1g, const float* __restrict__ wcb,
    const bf16* __restrict__ wfc2b, const float* __restrict__ bfc2,
    float* __restrict__ out)
{
    // LDS map (51,200 B -> 3 blocks/CU):
    //   [0, 30720)     : Us ushort [32][480] swizzled (phase C out / D in)
    //                    (phase A alias: Xs float [32][164] = 20,992 B)
    //   [30720, 40960) : As ushort [32][160] swizzled (normalized y, bf16)
    //   [40960, 51200) : Gs ushort [32][160] linear   (gm tile, bf16)
    __shared__ __align__(16) char lds[51200];
    float* Xs = (float*)lds;
    char* UsB = lds;
    char* AsB = lds + 30720;
    char* GsB = lds + 40960;

    int tid = threadIdx.x, wave = tid>>6, lane = tid&63, m = lane&15, q = lane>>4;
    int rt = wave&1, chh = wave>>1;
    int blk = blockIdx.x; int bb = blk/98; int hw0 = (blk - bb*98)*32;
    size_t pos0 = (size_t)bb*HWn + hw0;
    const float* xb = x + (size_t)bb*Cn*HWn + hw0;

    // ---- phase A: stage x transposed -> Xs[p][164] (HBM loads issue first)
    for (int idx = tid; idx < 160*32; idx += 256){
        int c = idx >> 5, p = idx & 31;
        Xs[p*164 + c] = xb[(size_t)c*HWn + p];
    }

    // ---- phase 0: gm for rows rt*16..+15, chans chh*80..+79 -> Gs (overlaps A's latency)
    {
        s8v a0[15];
        #pragma unroll
        for (int kb = 0; kb < 15; ++kb){
            const bf16* src = (kb < 5) ? gT : (kb < 10 ? xhT : xwT);
            int kc = (kb - (kb < 5 ? 0 : (kb < 10 ? 5 : 10)))*32 + q*8;
            a0[kb] = *(const s8v*)((const unsigned short*)src + (pos0 + rt*16 + m)*160 + kc);
        }
        #pragma unroll
        for (int s = 0; s < 5; ++s){
            int o = chh*80 + s*16 + m;
            const unsigned short* W2 = (const unsigned short*)wf2b + (size_t)o*480 + q*8;
            s8v bw[15];
            #pragma unroll
            for (int kb = 0; kb < 15; ++kb) bw[kb] = *(const s8v*)(W2 + kb*32);
            f4v acc = {0.f,0.f,0.f,0.f};
            #pragma unroll
            for (int kb = 0; kb < 15; ++kb) acc = MFMA(a0[kb], bw[kb], acc);
            #pragma unroll
            for (int r = 0; r < 4; ++r)
                *(unsigned short*)(GsB + (rt*16 + q*4 + r)*320 + o*2) = f2bits(acc[r]);
        }
    }
    __syncthreads();   // Xs + Gs ready

    // ---- phase B: y = x+gm; mean/var; As <- bf16((y-mu)*rstd) swizzled
    {
        int p = tid >> 3, q8 = tid & 7; int c0 = q8*20;
        float y[20]; float s = 0.f, ss = 0.f;
        #pragma unroll
        for (int j = 0; j < 5; ++j){
            u4v gv = *(const u4v*)(GsB + p*320 + (c0 + j*4)*2);
            f4v xv = *(const f4v*)&Xs[p*164 + c0 + j*4];
            #pragma unroll
            for (int t = 0; t < 4; ++t){
                float vv = xv[t] + bits2f(gv[t]);
                y[j*4 + t] = vv; s += vv; ss += vv*vv;
            }
        }
        s += __shfl_xor(s, 1); ss += __shfl_xor(ss, 1);
        s += __shfl_xor(s, 2); ss += __shfl_xor(ss, 2);
        s += __shfl_xor(s, 4); ss += __shfl_xor(ss, 4);
        float mean = s * (1.f/160.f);
        float var  = ss * (1.f/160.f) - mean*mean;
        float rstd = rsqrtf(var + 1e-5f);
        int xr = (p&7)<<4;
        #pragma unroll
        for (int j = 0; j < 5; ++j){
            u4v pk;
            #pragma unroll
            for (int t = 0; t < 4; ++t) pk[t] = f2bits((y[j*4 + t] - mean)*rstd);
            int off = (p*320 + (c0 + j*4)*2) ^ xr;
            *(u4v*)(AsB + off) = pk;
        }
    }
    __syncthreads();   // As ready; Xs reads done (Us writes below overwrite Xs)

    // ---- phase C: fc1. wave (rt,chh): rows rt*16.., feature steps chh*15..+14
    {
        s8v a1[5];
        {
            int row = rt*16 + m; int xr = (row&7)<<4;
            #pragma unroll
            for (int kb = 0; kb < 5; ++kb){
                int off = (row*320 + (q*8 + kb*32)*2) ^ xr;
                a1[kb] = *(const s8v*)(AsB + off);
            }
        }
        const unsigned short* W1 = (const unsigned short*)wfc1g + ((size_t)chh*15*16 + m)*160 + q*8;
        s8v b0[5], b1[5];
        #pragma unroll
        for (int kb = 0; kb < 5; ++kb) b0[kb] = *(const s8v*)(W1 + kb*32);
        #pragma unroll
        for (int s = 0; s < 15; ++s){
            if (s + 1 < 15){
                const unsigned short* Wn = W1 + (size_t)(s+1)*2560;
                #pragma unroll
                for (int kb = 0; kb < 5; ++kb) b1[kb] = *(const s8v*)(Wn + kb*32);
            }
            f4v acc = {0.f,0.f,0.f,0.f};
            #pragma unroll
            for (int kb = 0; kb < 5; ++kb) acc = MFMA(a1[kb], b0[kb], acc);
            int o = (chh*15 + s)*16 + m;
            float wc = wcb[o];
            #pragma unroll
            for (int r = 0; r < 4; ++r){
                int row = rt*16 + q*4 + r;
                int off = (row*960 + o*2) ^ ((row&7)<<4);
                *(unsigned short*)(UsB + off) = f2bits(gelu_f(acc[r] + wc));
            }
            if (s + 1 < 15){
                #pragma unroll
                for (int kb = 0; kb < 5; ++kb) b0[kb] = b1[kb];
            }
        }
    }
    __syncthreads();   // u ready in LDS

    // ---- phase D: fc2 + residual (gm from LDS). wave (rt,chh): rows rt*16.., out ch chh*80..
    {
        s8v a2[15];
        {
            int row = rt*16 + m; int xr = (row&7)<<4;
            #pragma unroll
            for (int kb = 0; kb < 15; ++kb){
                int off = (row*960 + (q*8 + kb*32)*2) ^ xr;
                a2[kb] = *(const s8v*)(UsB + off);
            }
        }
        #pragma unroll
        for (int s = 0; s < 5; ++s){
            int o = chh*80 + s*16 + m;
            const unsigned short* W2 = (const unsigned short*)wfc2b + (size_t)o*480 + q*8;
            s8v b2[15];
            #pragma unroll
            for (int kb = 0; kb < 15; ++kb) b2[kb] = *(const s8v*)(W2 + kb*32);
            f4v acc = {0.f,0.f,0.f,0.f};
            #pragma unroll
            for (int kb = 0; kb < 15; ++kb) acc = MFMA(a2[kb], b2[kb], acc);
            float bias = bfc2[o];
            const float* xp = x + (size_t)bb*Cn*HWn + (size_t)o*HWn + hw0 + rt*16 + q*4;
            f4v x4 = *(const f4v*)xp;
            f4v o4;
            #pragma unroll
            for (int r = 0; r < 4; ++r){
                int row = rt*16 + q*4 + r;
                float gmv = bits2f(*(const unsigned short*)(GsB + row*320 + o*2));
                o4[r] = x4[r] + gmv + acc[r] + bias;
            }
            float* op = out + (size_t)bb*Cn*HWn + (size_t)o*HWn + hw0 + rt*16 + q*4;
            *(f4v*)op = o4;
        }
    }
}

extern "C" void kernel_launch(void* const* d_in, const int* in_sizes, int n_in,
                              void* d_out, int out_size, void* d_ws, size_t ws_size,
                              hipStream_t stream)
{
    (void)in_sizes; (void)n_in; (void)out_size; (void)ws_size;
    const float* x     = (const float*)d_in[0];
    const float* bn1g  = (const float*)d_in[1];
    const float* bn1b  = (const float*)d_in[2];
    const float* bn1m  = (const float*)d_in[3];
    const float* bn1v  = (const float*)d_in[4];
    const float* wt    = (const float*)d_in[5];
    const float* bt    = (const float*)d_in[6];
    const float* wb    = (const float*)d_in[7];
    const float* bb    = (const float*)d_in[8];
    const float* wr    = (const float*)d_in[9];
    const float* br    = (const float*)d_in[10];
    const float* wl    = (const float*)d_in[11];
    const float* bl    = (const float*)d_in[12];
    const float* wc    = (const float*)d_in[13];
    const float* bc    = (const float*)d_in[14];
    const float* wf1   = (const float*)d_in[15];
    const float* bf1   = (const float*)d_in[16];
    const float* bn2g  = (const float*)d_in[17];
    const float* bn2b  = (const float*)d_in[18];
    const float* bn2m  = (const float*)d_in[19];
    const float* bn2v  = (const float*)d_in[20];
    const float* wph   = (const float*)d_in[21];
    const float* bph   = (const float*)d_in[22];
    const float* wpw   = (const float*)d_in[23];
    const float* bpw   = (const float*)d_in[24];
    const float* wf2   = (const float*)d_in[25];
    const float* lng   = (const float*)d_in[26];
    const float* lnb   = (const float*)d_in[27];
    const float* wfc1  = (const float*)d_in[28];
    const float* bfc1  = (const float*)d_in[29];
    const float* wfc2  = (const float*)d_in[30];
    const float* bfc2v = (const float*)d_in[31];
    float* outp = (float*)d_out;

    // workspace layout (bytes); bf16 [Pn][160] buffer = 32,112,640 B
    const size_t PC2 = (size_t)Pn*160*2;
    char* ws = (char*)d_ws;
    bf16* y5T  = (bf16*)(ws + 1*PC2);
    bf16* gT   = (bf16*)(ws + 2*PC2);
    bf16* xhT  = (bf16*)(ws + 3*PC2);
    bf16* xwT  = (bf16*)(ws + 4*PC2);
    char* wsw  = ws + 6*PC2;                       // weights @ 192,675,840
    bf16*  wcat  = (bf16*)(wsw + 0);
    bf16*  wf1b  = (bf16*)(wsw + 51200);
    bf16*  wf2b  = (bf16*)(wsw + 102400);
    bf16*  wfc1g = (bf16*)(wsw + 256000);
    bf16*  wfc2b = (bf16*)(wsw + 409600);
    bf16*  wphb  = (bf16*)(wsw + 563200);
    bf16*  wpwb  = (bf16*)(wsw + 571392);
    float* bcat  = (float*)(wsw + 579584);
    float* epsv  = (float*)(wsw + 580224);
    float* eptv  = (float*)(wsw + 580864);
    float* wgs   = (float*)(wsw + 581504);
    float* wcb   = (float*)(wsw + 583424);

    const int GP = Pn/64;     // 1568
    const int GS = Bn*56;     // 1792
    const int GF = Pn/32;     // 3136

    k0_prep<<<1136, 256, 0, stream>>>(wt, wb, wr, wl, wc, bt, bb, br, bl, bc,
                                      wf1, bf1, bn2g, bn2b, bn2m, bn2v,
                                      wf2, wfc1, wfc2, wph, wpw,
                                      lng, lnb, bfc1,
                                      wcat, wf1b, wf2b, wfc1g, wfc2b, wphb, wpwb,
                                      bcat, epsv, eptv, wgs, wcb);
    k12_bn_conv5 <<<GP, 256, 0, stream>>>(x, bn1g, bn1b, bn1m, bn1v, wcat, bcat, y5T);
    k3_wf1       <<<GP, 256, 0, stream>>>(y5T, wf1b, epsv, eptv, gT);
    k4_projh     <<<GS, 256, 0, stream>>>(gT, wphb, bph, xhT);
    k5_projw     <<<GS, 256, 0, stream>>>(gT, wpwb, bpw, xwT);
    k678_mlp     <<<GF, 256, 0, stream>>>(x, gT, xhT, xwT, wf2b,
                                          wfc1g, wcb, wfc2b, bfc2v, outp);
}

// Round 10
// 468.556 us; speedup vs baseline: 1.0695x; 1.0695x over previous
//
#include <hip/hip_runtime.h>
#include <hip/hip_bf16.h>
#include <math.h>

typedef __hip_bfloat16 bf16;
typedef __attribute__((ext_vector_type(8))) short s8v;   // 8 bf16 bit-carrier (4 VGPR)
typedef __attribute__((ext_vector_type(4))) float f4v;   // MFMA 16x16 accumulator / float4
typedef __attribute__((ext_vector_type(4))) unsigned short u4v; // 8B bf16 carrier

#define Bn  32
#define Cn  160
#define HWn 3136
#define Pn  100352

__device__ __forceinline__ float b2f(bf16 v){ return __bfloat162float(v); }
__device__ __forceinline__ bf16  f2b(float v){ return __float2bfloat16(v); }
__device__ __forceinline__ float bits2f(unsigned short u){
    union { float f; unsigned int i; } x; x.i = ((unsigned int)u) << 16; return x.f;
}
__device__ __forceinline__ unsigned short f2bits(float v){
    union { unsigned short us; bf16 b; } cv; cv.b = f2b(v); return cv.us;
}
// Fast gelu: erf via Abramowitz-Stegun 7.1.26 (|eps| <= 1.5e-7 absolute on erf),
// v_rcp_f32 (1 inst, ~1 ulp) instead of the ~12-inst IEEE divide. rcpf error is
// 5+ orders below the bf16 rounding applied to every gelu output downstream.
// (R4 failed identically WITHOUT rcpf -> prior container failures were infra.)
__device__ __forceinline__ float gelu_f(float x){
    float ax = fabsf(x) * 0.7071067811865476f;
    float t  = __builtin_amdgcn_rcpf(1.0f + 0.3275911f*ax);
    float p  = ((((1.061405429f*t - 1.453152027f)*t + 1.421413741f)*t
                 - 0.284496736f)*t + 0.254829592f)*t;
    float e  = __expf(-ax*ax);
    float erfv = 1.0f - p*e;            // erf(|x|/sqrt2)
    float s = (x >= 0.f) ? erfv : -erfv;
    return 0.5f*x*(1.0f + s);
}

#define MFMA(a,b,c) __builtin_amdgcn_mfma_f32_16x16x32_bf16((a),(b),(c),0,0,0)

// ---------------- K0: weight prep (fp32 -> bf16, concat/pad, LN folding) ----------------
__global__ __launch_bounds__(256) void k0_prep(
    const float* __restrict__ wt, const float* __restrict__ wb_, const float* __restrict__ wr,
    const float* __restrict__ wl, const float* __restrict__ wc,
    const float* __restrict__ bt, const float* __restrict__ bb_, const float* __restrict__ br,
    const float* __restrict__ bl, const float* __restrict__ bc,
    const float* __restrict__ wf1, const float* __restrict__ bf1,
    const float* __restrict__ g2, const float* __restrict__ b2, const float* __restrict__ m2, const float* __restrict__ v2,
    const float* __restrict__ wf2, const float* __restrict__ wfc1, const float* __restrict__ wfc2,
    const float* __restrict__ wph, const float* __restrict__ wpw,
    const float* __restrict__ lng, const float* __restrict__ lnb, const float* __restrict__ bfc1,
    bf16* wcat, bf16* wf1b, bf16* wf2b, bf16* wfc1g, bf16* wfc2b, bf16* wphb, bf16* wpwb,
    float* bcat, float* epsv, float* eptv, float* wgs, float* wcb)
{
    int idx = blockIdx.x*256 + threadIdx.x;
    if (idx < 25600){ int o = idx/160, k = idx - o*160; int gi = o>>5, oo = o&31;
        const float* wp = gi==0?wt: gi==1?wb_: gi==2?wr: gi==3?wl: wc;
        wcat[idx] = f2b(wp[oo*160+k]); return; }
    idx -= 25600;
    if (idx < 25600){ wf1b[idx] = f2b(wf1[idx]); return; }
    idx -= 25600;
    if (idx < 76800){ wf2b[idx] = f2b(wf2[idx]); return; }
    idx -= 76800;
    if (idx < 76800){ int f = idx/160, c = idx - f*160;
        wfc1g[idx] = f2b(wfc1[f*160+c] * lng[c]); return; }
    idx -= 76800;
    if (idx < 76800){ wfc2b[idx] = f2b(wfc2[idx]); return; }
    idx -= 76800;
    if (idx < 4096){ int v = idx>>6, w = idx&63;
        wphb[idx] = (v<56 && w<56) ? f2b(wph[v*56+w]) : f2b(0.f); return; }
    idx -= 4096;
    if (idx < 4096){ int v = idx>>6, w = idx&63;
        wpwb[idx] = (v<56 && w<56) ? f2b(wpw[v*56+w]) : f2b(0.f); return; }
    idx -= 4096;
    if (idx < 160){ int o = idx; int gi = o>>5, oo = o&31;
        const float* bp = gi==0?bt: gi==1?bb_: gi==2?br: gi==3?bl: bc;
        bcat[o] = bp[oo]; return; }
    idx -= 160;
    if (idx < 160){ int o = idx; float s = g2[o]*rsqrtf(v2[o]+1e-5f);
        epsv[o] = s; eptv[o] = (bf1[o]-m2[o])*s + b2[o]; return; }
    idx -= 160;
    if (idx < 480){ int o = idx; float sg = 0.f, sb = 0.f;
        const float* wr_ = wfc1 + (size_t)o*160;
        for (int c = 0; c < 160; ++c){ float w = wr_[c]; sg += w*lng[c]; sb += w*lnb[c]; }
        wgs[o] = sg; wcb[o] = sb + bfc1[o]; return; }
}

// ---------------- K12: fused gelu(bn1(x)) -> LDS A-tile -> conv5 GEMM ----------------
__global__ __launch_bounds__(256) void k12_bn_conv5(const float* __restrict__ x,
    const float* __restrict__ g, const float* __restrict__ b,
    const float* __restrict__ m_, const float* __restrict__ v,
    const bf16* __restrict__ wcat, const float* __restrict__ bcat, bf16* __restrict__ y5T)
{
    __shared__ __align__(16) unsigned short Bs[2][16*168];
    __shared__ __align__(16) char AsB[64*320];
    __shared__ float sc[160], sh[160];
    int tid = threadIdx.x, wave = tid>>6, lane = tid&63, m = lane&15, q = lane>>4;
    int blk = blockIdx.x; int bb = blk/49; int hw0 = (blk - bb*49)*64;
    if (tid < 160){
        float s = g[tid] * rsqrtf(v[tid] + 1e-5f);
        sc[tid] = s; sh[tid] = b[tid] - m_[tid]*s;
    }
    { const s8v* sp = (const s8v*)((const unsigned short*)wcat);
      for (int c = tid; c < 320; c += 256){ int row = c/20, col = (c - row*20)*8;
          *(s8v*)&Bs[0][row*168 + col] = sp[c]; } }
    __syncthreads();   // sc/sh + Bs[0] ready
    const float* xb = x + (size_t)bb*Cn*HWn + hw0;
    for (int idx = tid; idx < 160*64; idx += 256){
        int c = idx >> 6, p = idx & 63;
        float val = xb[(size_t)c*HWn + p];
        unsigned short us = f2bits(gelu_f(val*sc[c] + sh[c]));
        int off = (p*320 + c*2) ^ ((p&7)<<4);
        *(unsigned short*)(AsB + off) = us;
    }
    __syncthreads();   // As ready
    size_t pos0 = (size_t)bb*HWn + hw0;
    s8v a[5];
    {
        int row = wave*16 + m; int xr = (row&7)<<4;
        #pragma unroll
        for (int kb = 0; kb < 5; ++kb){
            int off = (row*320 + (q*8 + kb*32)*2) ^ xr;
            a[kb] = *(const s8v*)(AsB + off);
        }
    }
    for (int s = 0; s < 10; ++s){
        if (s+1 < 10){
            const s8v* sp = (const s8v*)((const unsigned short*)wcat + (size_t)(s+1)*2560);
            for (int c = tid; c < 320; c += 256){ int row = c/20, col = (c - row*20)*8;
                *(s8v*)&Bs[(s+1)&1][row*168 + col] = sp[c]; }
        }
        f4v acc = {0.f,0.f,0.f,0.f};
        const unsigned short* Bp = &Bs[s&1][m*168 + q*8];
        #pragma unroll
        for (int kb = 0; kb < 5; ++kb) acc = MFMA(a[kb], *(const s8v*)(Bp + kb*32), acc);
        float bias = bcat[s*16 + m];
        bf16* yo = y5T + (pos0 + wave*16 + q*4)*160 + s*16 + m;
        #pragma unroll
        for (int r = 0; r < 4; ++r) yo[r*160] = f2b(acc[r] + bias);
        __syncthreads();
    }
}

// ---------------- K3: shifted-A GEMM + bn2 + gelu -> gT ----------------
__global__ __launch_bounds__(256) void k3_wf1(const bf16* __restrict__ y5T,
    const bf16* __restrict__ wf1b, const float* __restrict__ epsv, const float* __restrict__ eptv,
    bf16* __restrict__ gT)
{
    __shared__ __align__(16) unsigned short Bs[2][16*168];
    int tid = threadIdx.x, wave = tid>>6, lane = tid&63, m = lane&15, q = lane>>4;
    int blk = blockIdx.x; int bb = blk/49; int hw0 = (blk - bb*49)*64;
    size_t pos0 = (size_t)bb*HWn + hw0;
    int phw = hw0 + wave*16 + m; int h = phw/56, w = phw - h*56;
    s8v a[5];
    #pragma unroll
    for (int kb = 0; kb < 5; ++kb){
        int h2 = h, w2 = w; bool ok = true;
        if      (kb == 0){ h2 = h+1; ok = (h2 < 56); }
        else if (kb == 1){ h2 = h-1; ok = (h2 >= 0); }
        else if (kb == 2){ w2 = w-1; ok = (w2 >= 0); }
        else if (kb == 3){ w2 = w+1; ok = (w2 < 56); }
        if (ok){
            const unsigned short* Ap = (const unsigned short*)y5T +
                ((size_t)bb*HWn + h2*56 + w2)*160 + kb*32 + q*8;
            a[kb] = *(const s8v*)Ap;
        } else {
            a[kb] = (s8v){0,0,0,0,0,0,0,0};
        }
    }
    { const s8v* sp = (const s8v*)((const unsigned short*)wf1b);
      for (int c = tid; c < 320; c += 256){ int row = c/20, col = (c - row*20)*8;
          *(s8v*)&Bs[0][row*168 + col] = sp[c]; } }
    __syncthreads();
    for (int s = 0; s < 10; ++s){
        if (s+1 < 10){
            const s8v* sp = (const s8v*)((const unsigned short*)wf1b + (size_t)(s+1)*2560);
            for (int c = tid; c < 320; c += 256){ int row = c/20, col = (c - row*20)*8;
                *(s8v*)&Bs[(s+1)&1][row*168 + col] = sp[c]; }
        }
        f4v acc = {0.f,0.f,0.f,0.f};
        const unsigned short* Bp = &Bs[s&1][m*168 + q*8];
        #pragma unroll
        for (int kb = 0; kb < 5; ++kb) acc = MFMA(a[kb], *(const s8v*)(Bp + kb*32), acc);
        int o = s*16 + m;
        float es = epsv[o], et = eptv[o];
        bf16* go = gT + (pos0 + wave*16 + q*4)*160 + o;
        #pragma unroll
        for (int r = 0; r < 4; ++r) go[r*160] = f2b(gelu_f(acc[r]*es + et));
        __syncthreads();
    }
}

// ---------------- K4: proj_h MFMA ----------------
__global__ __launch_bounds__(256) void k4_projh(const bf16* __restrict__ gT,
    const bf16* __restrict__ wphb, const float* __restrict__ bph, bf16* __restrict__ xhT)
{
    __shared__ __align__(16) unsigned short gS[160*72];
    int tid = threadIdx.x, wave = tid>>6, lane = tid&63, m = lane&15, q = lane>>4;
    int blk = blockIdx.x; int b = blk/56, h = blk - b*56;
    const unsigned short* ga = (const unsigned short*)gT + ((size_t)b*HWn + h*56)*160;
    for (int idx = tid; idx < 56*160; idx += 256){
        int w = idx/160, c = idx - w*160;
        gS[c*72 + w] = ga[idx];
    }
    for (int idx = tid; idx < 160*8; idx += 256){
        int c = idx>>3, w = 56 + (idx&7);
        gS[c*72 + w] = 0;
    }
    __syncthreads();
    int v0 = wave*16;
    s8v a[2];
    #pragma unroll
    for (int kb = 0; kb < 2; ++kb)
        a[kb] = *(const s8v*)((const unsigned short*)wphb + (v0+m)*64 + kb*32 + q*8);
    int v = v0 + q*4;
    for (int s = 0; s < 10; ++s){
        f4v acc = {0.f,0.f,0.f,0.f};
        const unsigned short* Bp = &gS[(s*16+m)*72 + q*8];
        #pragma unroll
        for (int kb = 0; kb < 2; ++kb) acc = MFMA(a[kb], *(const s8v*)(Bp + kb*32), acc);
        #pragma unroll
        for (int r = 0; r < 4; ++r){
            int vv = v + r;
            if (vv < 56)
                xhT[((size_t)b*HWn + h*56 + vv)*160 + s*16 + m] = f2b(acc[r] + bph[vv]);
        }
    }
}

// ---------------- K5: proj_w MFMA ----------------
__global__ __launch_bounds__(256) void k5_projw(const bf16* __restrict__ gT,
    const bf16* __restrict__ wpwb, const float* __restrict__ bpw, bf16* __restrict__ xwT)
{
    __shared__ __align__(16) unsigned short gS[160*72];
    int tid = threadIdx.x, wave = tid>>6, lane = tid&63, m = lane&15, q = lane>>4;
    int blk = blockIdx.x; int b = blk/56, w = blk - b*56;
    const unsigned short* gbase = (const unsigned short*)gT + ((size_t)b*HWn + w)*160;
    for (int idx = tid; idx < 56*160; idx += 256){
        int hh = idx/160, c = idx - hh*160;
        gS[c*72 + hh] = gbase[(size_t)hh*56*160 + c];
    }
    for (int idx = tid; idx < 160*8; idx += 256){
        int c = idx>>3, hh = 56 + (idx&7);
        gS[c*72 + hh] = 0;
    }
    __syncthreads();
    int v0 = wave*16;
    s8v a[2];
    #pragma unroll
    for (int kb = 0; kb < 2; ++kb)
        a[kb] = *(const s8v*)((const unsigned short*)wpwb + (v0+m)*64 + kb*32 + q*8);
    int v = v0 + q*4;
    for (int s = 0; s < 10; ++s){
        f4v acc = {0.f,0.f,0.f,0.f};
        const unsigned short* Bp = &gS[(s*16+m)*72 + q*8];
        #pragma unroll
        for (int kb = 0; kb < 2; ++kb) acc = MFMA(a[kb], *(const s8v*)(Bp + kb*32), acc);
        #pragma unroll
        for (int r = 0; r < 4; ++r){
            int vv = v + r;
            if (vv < 56)
                xwT[((size_t)b*HWn + vv*56 + w)*160 + s*16 + m] = f2b(acc[r] + bpw[vv]);
        }
    }
}

// ---------------- K6: wf2 GEMM (K=480 concat) -> gm bf16 BHWC ----------------
__global__ __launch_bounds__(256) void k6_wf2(const bf16* __restrict__ gT,
    const bf16* __restrict__ xhT, const bf16* __restrict__ xwT,
    const bf16* __restrict__ wf2b, bf16* __restrict__ gm)
{
    __shared__ __align__(16) unsigned short Bs[2][16*488];
    int tid = threadIdx.x, wave = tid>>6, lane = tid&63, m = lane&15, q = lane>>4;
    size_t pos0 = (size_t)blockIdx.x*64;
    size_t prow = (pos0 + wave*16 + m)*160;
    s8v a[15];
    #pragma unroll
    for (int kb = 0; kb < 15; ++kb){
        const bf16* src = (kb < 5) ? gT : (kb < 10 ? xhT : xwT);
        int kc = (kb - (kb < 5 ? 0 : (kb < 10 ? 5 : 10)))*32 + q*8;
        a[kb] = *(const s8v*)((const unsigned short*)src + prow + kc);
    }
    { const s8v* sp = (const s8v*)((const unsigned short*)wf2b);
      for (int c = tid; c < 960; c += 256){ int row = c/60, col = (c - row*60)*8;
          *(s8v*)&Bs[0][row*488 + col] = sp[c]; } }
    __syncthreads();
    for (int s = 0; s < 10; ++s){
        if (s+1 < 10){
            const s8v* sp = (const s8v*)((const unsigned short*)wf2b + (size_t)(s+1)*7680);
            for (int c = tid; c < 960; c += 256){ int row = c/60, col = (c - row*60)*8;
                *(s8v*)&Bs[(s+1)&1][row*488 + col] = sp[c]; }
        }
        f4v acc = {0.f,0.f,0.f,0.f};
        const unsigned short* Bp = &Bs[s&1][m*488 + q*8];
        #pragma unroll
        for (int kb = 0; kb < 15; ++kb) acc = MFMA(a[kb], *(const s8v*)(Bp + kb*32), acc);
        bf16* go = gm + (pos0 + wave*16 + q*4)*160 + s*16 + m;
        #pragma unroll
        for (int r = 0; r < 4; ++r) go[r*160] = f2b(acc[r]);
        __syncthreads();
    }
}

// ---------------- K78: fused channelMix, LN applied in-activation ----------------
// As := bf16((y-mu)*rstd)  (y = x+gm). Then fc1(ln(y)) = Wg@As + wcb exactly.
// LDS = 40,960 B; launch bounds (256,3) -- R6 showed (256,4) forces a 64-VGPR
// clamp and scratch spill in phase D.
__global__ __launch_bounds__(256,3) void k78_mlp(const float* __restrict__ x,
    const bf16* __restrict__ gm,
    const bf16* __restrict__ wfc1g, const float* __restrict__ wcb,
    const bf16* __restrict__ wfc2b, const float* __restrict__ bfc2,
    float* __restrict__ out)
{
    // LDS map (40,960 B):
    //   [0, 30720)     : Us ushort [32][480] swizzled (phase C out / D in)
    //                    (phase A alias: Xs float [32][164] = 20,992 B)
    //   [30720, 40960) : As ushort [32][160] swizzled (normalized y, bf16)
    __shared__ __align__(16) char lds[40960];
    float* Xs = (float*)lds;
    char* UsB = lds;
    char* AsB = lds + 30720;

    int tid = threadIdx.x, wave = tid>>6, lane = tid&63, m = lane&15, q = lane>>4;
    int rt = wave&1, chh = wave>>1;
    int blk = blockIdx.x; int bb = blk/98; int hw0 = (blk - bb*98)*32;
    size_t pos0 = (size_t)bb*HWn + hw0;
    const float* xb = x + (size_t)bb*Cn*HWn + hw0;

    // ---- phase A: stage x transposed -> Xs[p][164]
    for (int idx = tid; idx < 160*32; idx += 256){
        int c = idx >> 5, p = idx & 31;
        Xs[p*164 + c] = xb[(size_t)c*HWn + p];
    }
    __syncthreads();

    // ---- phase B: y = x+gm; mean/var (8 thr x 20 ch); As <- bf16((y-mu)*rstd), swizzled
    {
        int p = tid >> 3, q8 = tid & 7; int c0 = q8*20;
        const unsigned short* gp = (const unsigned short*)gm + (pos0 + p)*160 + c0;
        float y[20]; float s = 0.f, ss = 0.f;
        #pragma unroll
        for (int j = 0; j < 5; ++j){
            u4v gv = *(const u4v*)(gp + j*4);
            f4v xv = *(const f4v*)&Xs[p*164 + c0 + j*4];
            #pragma unroll
            for (int t = 0; t < 4; ++t){
                float vv = xv[t] + bits2f(gv[t]);
                y[j*4 + t] = vv; s += vv; ss += vv*vv;
            }
        }
        s += __shfl_xor(s, 1); ss += __shfl_xor(ss, 1);
        s += __shfl_xor(s, 2); ss += __shfl_xor(ss, 2);
        s += __shfl_xor(s, 4); ss += __shfl_xor(ss, 4);
        float mean = s * (1.f/160.f);
        float var  = ss * (1.f/160.f) - mean*mean;
        float rstd = rsqrtf(var + 1e-5f);
        int xr = (p&7)<<4;
        #pragma unroll
        for (int j = 0; j < 5; ++j){
            u4v pk;
            #pragma unroll
            for (int t = 0; t < 4; ++t) pk[t] = f2bits((y[j*4 + t] - mean)*rstd);
            int off = (p*320 + (c0 + j*4)*2) ^ xr;
            *(u4v*)(AsB + off) = pk;
        }
    }
    __syncthreads();   // As ready; Xs reads done (Us writes below overwrite Xs)

    // ---- phase C: fc1. wave (rt,chh): rows rt*16.., feature steps chh*15..+14
    {
        s8v a1[5];
        {
            int row = rt*16 + m; int xr = (row&7)<<4;
            #pragma unroll
            for (int kb = 0; kb < 5; ++kb){
                int off = (row*320 + (q*8 + kb*32)*2) ^ xr;
                a1[kb] = *(const s8v*)(AsB + off);
            }
        }
        const unsigned short* W1 = (const unsigned short*)wfc1g + ((size_t)chh*15*16 + m)*160 + q*8;
        s8v b0[5], b1[5];
        #pragma unroll
        for (int kb = 0; kb < 5; ++kb) b0[kb] = *(const s8v*)(W1 + kb*32);
        #pragma unroll
        for (int s = 0; s < 15; ++s){
            if (s + 1 < 15){
                const unsigned short* Wn = W1 + (size_t)(s+1)*2560;
                #pragma unroll
                for (int kb = 0; kb < 5; ++kb) b1[kb] = *(const s8v*)(Wn + kb*32);
            }
            f4v acc = {0.f,0.f,0.f,0.f};
            #pragma unroll
            for (int kb = 0; kb < 5; ++kb) acc = MFMA(a1[kb], b0[kb], acc);
            int o = (chh*15 + s)*16 + m;
            float wc = wcb[o];
            #pragma unroll
            for (int r = 0; r < 4; ++r){
                int row = rt*16 + q*4 + r;
                int off = (row*960 + o*2) ^ ((row&7)<<4);
                *(unsigned short*)(UsB + off) = f2bits(gelu_f(acc[r] + wc));
            }
            if (s + 1 < 15){
                #pragma unroll
                for (int kb = 0; kb < 5; ++kb) b0[kb] = b1[kb];
            }
        }
    }
    __syncthreads();   // u ready in LDS

    // ---- phase D: fc2 + residual. wave (rt,chh): rows rt*16.., out ch chh*80..+79
    {
        s8v a2[15];
        {
            int row = rt*16 + m; int xr = (row&7)<<4;
            #pragma unroll
            for (int kb = 0; kb < 15; ++kb){
                int off = (row*960 + (q*8 + kb*32)*2) ^ xr;
                a2[kb] = *(const s8v*)(UsB + off);
            }
        }
        #pragma unroll
        for (int s = 0; s < 5; ++s){
            int o = chh*80 + s*16 + m;
            const unsigned short* W2 = (const unsigned short*)wfc2b + (size_t)o*480 + q*8;
            s8v b2[15];
            #pragma unroll
            for (int kb = 0; kb < 15; ++kb) b2[kb] = *(const s8v*)(W2 + kb*32);
            f4v acc = {0.f,0.f,0.f,0.f};
            #pragma unroll
            for (int kb = 0; kb < 15; ++kb) acc = MFMA(a2[kb], b2[kb], acc);
            float bias = bfc2[o];
            const float* xp = x + (size_t)bb*Cn*HWn + (size_t)o*HWn + hw0 + rt*16 + q*4;
            f4v x4 = *(const f4v*)xp;
            const unsigned short* gmp = (const unsigned short*)gm + (pos0 + rt*16 + q*4)*160 + o;
            f4v o4;
            #pragma unroll
            for (int r = 0; r < 4; ++r)
                o4[r] = x4[r] + bits2f(gmp[(size_t)r*160]) + acc[r] + bias;
            float* op = out + (size_t)bb*Cn*HWn + (size_t)o*HWn + hw0 + rt*16 + q*4;
            *(f4v*)op = o4;
        }
    }
}

extern "C" void kernel_launch(void* const* d_in, const int* in_sizes, int n_in,
                              void* d_out, int out_size, void* d_ws, size_t ws_size,
                              hipStream_t stream)
{
    (void)in_sizes; (void)n_in; (void)out_size; (void)ws_size;
    const float* x     = (const float*)d_in[0];
    const float* bn1g  = (const float*)d_in[1];
    const float* bn1b  = (const float*)d_in[2];
    const float* bn1m  = (const float*)d_in[3];
    const float* bn1v  = (const float*)d_in[4];
    const float* wt    = (const float*)d_in[5];
    const float* bt    = (const float*)d_in[6];
    const float* wb    = (const float*)d_in[7];
    const float* bb    = (const float*)d_in[8];
    const float* wr    = (const float*)d_in[9];
    const float* br    = (const float*)d_in[10];
    const float* wl    = (const float*)d_in[11];
    const float* bl    = (const float*)d_in[12];
    const float* wc    = (const float*)d_in[13];
    const float* bc    = (const float*)d_in[14];
    const float* wf1   = (const float*)d_in[15];
    const float* bf1   = (const float*)d_in[16];
    const float* bn2g  = (const float*)d_in[17];
    const float* bn2b  = (const float*)d_in[18];
    const float* bn2m  = (const float*)d_in[19];
    const float* bn2v  = (const float*)d_in[20];
    const float* wph   = (const float*)d_in[21];
    const float* bph   = (const float*)d_in[22];
    const float* wpw   = (const float*)d_in[23];
    const float* bpw   = (const float*)d_in[24];
    const float* wf2   = (const float*)d_in[25];
    const float* lng   = (const float*)d_in[26];
    const float* lnb   = (const float*)d_in[27];
    const float* wfc1  = (const float*)d_in[28];
    const float* bfc1  = (const float*)d_in[29];
    const float* wfc2  = (const float*)d_in[30];
    const float* bfc2v = (const float*)d_in[31];
    float* outp = (float*)d_out;

    // workspace layout (bytes); bf16 [Pn][160] buffer = 32,112,640 B
    const size_t PC2 = (size_t)Pn*160*2;
    char* ws = (char*)d_ws;
    bf16* y5T  = (bf16*)(ws + 1*PC2);
    bf16* gT   = (bf16*)(ws + 2*PC2);
    bf16* xhT  = (bf16*)(ws + 3*PC2);
    bf16* xwT  = (bf16*)(ws + 4*PC2);
    bf16* gm   = (bf16*)(ws + 5*PC2);
    char* wsw  = ws + 6*PC2;                       // weights @ 192,675,840
    bf16*  wcat  = (bf16*)(wsw + 0);
    bf16*  wf1b  = (bf16*)(wsw + 51200);
    bf16*  wf2b  = (bf16*)(wsw + 102400);
    bf16*  wfc1g = (bf16*)(wsw + 256000);
    bf16*  wfc2b = (bf16*)(wsw + 409600);
    bf16*  wphb  = (bf16*)(wsw + 563200);
    bf16*  wpwb  = (bf16*)(wsw + 571392);
    float* bcat  = (float*)(wsw + 579584);
    float* epsv  = (float*)(wsw + 580224);
    float* eptv  = (float*)(wsw + 580864);
    float* wgs   = (float*)(wsw + 581504);
    float* wcb   = (float*)(wsw + 583424);

    const int GP = Pn/64;     // 1568
    const int GS = Bn*56;     // 1792
    const int GF = Pn/32;     // 3136

    k0_prep<<<1136, 256, 0, stream>>>(wt, wb, wr, wl, wc, bt, bb, br, bl, bc,
                                      wf1, bf1, bn2g, bn2b, bn2m, bn2v,
                                      wf2, wfc1, wfc2, wph, wpw,
                                      lng, lnb, bfc1,
                                      wcat, wf1b, wf2b, wfc1g, wfc2b, wphb, wpwb,
                                      bcat, epsv, eptv, wgs, wcb);
    k12_bn_conv5 <<<GP, 256, 0, stream>>>(x, bn1g, bn1b, bn1m, bn1v, wcat, bcat, y5T);
    k3_wf1       <<<GP, 256, 0, stream>>>(y5T, wf1b, epsv, eptv, gT);
    k4_projh     <<<GS, 256, 0, stream>>>(gT, wphb, bph, xhT);
    k5_projw     <<<GS, 256, 0, stream>>>(gT, wpwb, bpw, xwT);
    k6_wf2       <<<GP, 256, 0, stream>>>(gT, xhT, xwT, wf2b, gm);
    k78_mlp      <<<GF, 256, 0, stream>>>(x, gm, wfc1g, wcb, wfc2b, bfc2v, outp);
}